// Round 9
// baseline (453.514 us; speedup 1.0000x reference)
//
#include <hip/hip_runtime.h>
#include <hip/hip_bf16.h>

// Problem constants
#define BB 8
#define NN 128
#define CC 256
#define HFD 160
#define WFD 160
#define SS 7
#define HB 8                 // h-block size for hierarchical integral
#define NHB (HFD / HB)       // 20 blocks
#define REGION_OUT_ELEMS (8*128*256*49)   // 12,845,056

typedef short short8 __attribute__((ext_vector_type(8)));
typedef float f32x4  __attribute__((ext_vector_type(4)));

// ---------------------------------------------------------------------------
// K0: convert proj_w [o][c] fp32 -> bf16, row-major (A-operand friendly).
// ---------------------------------------------------------------------------
__global__ __launch_bounds__(256) void k0_convert_w(const float* __restrict__ W,
                                                    __hip_bfloat16* __restrict__ Wb) {
    int o = blockIdx.x;
    int c = threadIdx.x;
    Wb[o * CC + c] = __float2bfloat16(W[o * CC + c]);
}

// ---------------------------------------------------------------------------
// K1'': fused transpose + w-cumsum + within-8-row-block h-cumsum.
//   in : fm[b][c][h][w]   (w fastest)
//   out: Ip[b][h][w][c]   (c fastest); Ip = w-prefix + h-prefix within block
// Thread (row=t&31, seg=t>>5) DIRECTLY loads its own 40-element scan segment
// (640 B contiguous per lane, NT), scans in registers, prefetches the next
// row before the barrier, applies the segment offset writer-side, and writes
// only final scanned values to LDS (f32x4). 2 barriers/row (was 4), no
// staging LDS traffic, HBM latency hidden under prev row's scan+transpose.
// ---------------------------------------------------------------------------
__global__ __launch_bounds__(128) void k1_rowscan_block(const float* __restrict__ fm,
                                                        float* __restrict__ Ip) {
    int bid = blockIdx.x;            // b*160 + c8*20 + hb
    int hb  = bid % NHB;
    int c8  = (bid / NHB) & 7;
    int b   = bid / (NHB * 8);
    int c0  = c8 * 32;
    int t   = threadIdx.x;

    __shared__ float tile[32][161];
    __shared__ float segsum[32][4];

    const int row = t & 31;
    const int seg = t >> 5;
    const int w0  = seg * 40;

    // this thread's global row-segment base: fm[b][c0+row][hb*HB][w0]
    const float* src = fm + (((size_t)(b * CC + c0 + row)) * HFD + hb * HB) * WFD + w0;

    f32x4 csum[10];
    #pragma unroll
    for (int it = 0; it < 10; ++it) csum[it] = (f32x4){0.f, 0.f, 0.f, 0.f};

    // prefetch row 0 (10 contiguous f32x4 per lane)
    f32x4 pre[10];
    #pragma unroll
    for (int k = 0; k < 10; ++k)
        pre[k] = __builtin_nontemporal_load((const f32x4*)(src + 4 * k));

    for (int hh = 0; hh < HB; ++hh) {
        // ---- register scan of this thread's segment ----
        float v[40];
        #pragma unroll
        for (int k = 0; k < 10; ++k) {
            v[4 * k + 0] = pre[k].x;
            v[4 * k + 1] = pre[k].y;
            v[4 * k + 2] = pre[k].z;
            v[4 * k + 3] = pre[k].w;
        }
        #pragma unroll
        for (int k = 1; k < 40; ++k) v[k] += v[k - 1];
        segsum[row][seg] = v[39];

        // ---- prefetch next row (latency hidden under fixup+transpose) ----
        if (hh + 1 < HB) {
            const float* s2 = src + (size_t)(hh + 1) * WFD;
            #pragma unroll
            for (int k = 0; k < 10; ++k)
                pre[k] = __builtin_nontemporal_load((const f32x4*)(s2 + 4 * k));
        }

        __syncthreads();   // B1: segsum visible; prev row's tile readers done

        // ---- writer-side segment offset + final scanned write to LDS ----
        float off = 0.f;
        if (seg > 0) off += segsum[row][0];
        if (seg > 1) off += segsum[row][1];
        if (seg > 2) off += segsum[row][2];
        #pragma unroll
        for (int k = 0; k < 10; ++k) {
            f32x4 sv = { v[4 * k + 0] + off, v[4 * k + 1] + off,
                         v[4 * k + 2] + off, v[4 * k + 3] + off };
            *(f32x4*)&tile[row][w0 + 4 * k] = sv;
        }

        __syncthreads();   // B2: scanned tile visible

        // ---- transposed read + running column sum + store ----
        int h = hb * HB + hh;
        size_t obase = (((size_t)b * HFD + h) * WFD) * CC + c0;
        #pragma unroll
        for (int it = 0; it < 10; ++it) {
            int vid = it * 128 + t;
            int w   = vid >> 3;        // 0..159
            int cg  = vid & 7;         // c = 4*cg within the 32-ch tile
            f32x4 cur;
            cur.x = tile[cg * 4 + 0][w];
            cur.y = tile[cg * 4 + 1][w];
            cur.z = tile[cg * 4 + 2][w];
            cur.w = tile[cg * 4 + 3][w];
            csum[it] += cur;
            *(f32x4*)(Ip + obase + (size_t)w * CC + cg * 4) = csum[it];
        }
    }
}

// ---------------------------------------------------------------------------
// K2': block-offset exclusive scan.  O[b][hb][w][c] = sum of block totals of
// all h-blocks before hb; block total of k = Ip[b][8k+7][w][c].
// One WG per (b,w), thread = c.  26 MB read + 26 MB write (tiny).
// ---------------------------------------------------------------------------
__global__ __launch_bounds__(256) void k2_offsets(const float* __restrict__ Ip,
                                                  float* __restrict__ O) {
    int w = blockIdx.x % WFD;
    int b = blockIdx.x / WFD;
    int c = threadIdx.x;
    float run = 0.f;
    #pragma unroll
    for (int hb = 0; hb < NHB; ++hb) {
        O[(((size_t)b * NHB + hb) * WFD + w) * CC + c] = run;
        run += Ip[(((size_t)b * HFD + (hb * HB + HB - 1)) * WFD + w) * CC + c];
    }
}

// ---------------------------------------------------------------------------
// K3: fused gather + GEMM, 512 threads (8 waves).
// bn swizzled so image b == XCD id.  Corner value = Ip(r,·) + O(r>>3,·).
// Gather: wave wv owns cells wv*6+k (k=0..5); wave 0 additionally cell 48.
// GEMM: wave wv owns o in [wv*32, wv*32+32): acc[2][4], 64 MFMA/wave.
// Epilogue: LDS-staged coalesced f32x4 NT stores.
// ---------------------------------------------------------------------------
#define PB_STRIDE 264   // bf16 elems; 528 B row

__global__ __launch_bounds__(512, 4) void k3_gather_gemm(
        const float* __restrict__ Ip, const float* __restrict__ O,
        const __hip_bfloat16* __restrict__ Wb,
        const float* __restrict__ bias, const float* __restrict__ bboxes,
        const int* __restrict__ ih_p, const int* __restrict__ iw_p,
        float* __restrict__ out) {
    int bid = blockIdx.x;
    int bn  = ((bid & 7) << 7) | (bid >> 3);   // image = bid&7 -> one image per XCD
    int b   = bn >> 7;
    int t   = threadIdx.x;
    const int lane = t & 63;
    const int wv   = t >> 6;     // 0..7

    __shared__ __align__(16) __hip_bfloat16 Pb[64 * PB_STRIDE];   // 33 KB
    float* stage = (float*)Pb;   // reused after GEMM: 128 o x 49 cells = 25 KB

    float bx1 = bboxes[bn * 4 + 0];
    float by1 = bboxes[bn * 4 + 1];
    float bx2 = bboxes[bn * 4 + 2];
    float by2 = bboxes[bn * 4 + 3];
    float sx = (float)WFD / (float)iw_p[0];
    float sy = (float)HFD / (float)ih_p[0];

    int x1 = min(max((int)floorf(bx1 * sx), 0), WFD - 1);
    int y1 = min(max((int)floorf(by1 * sy), 0), HFD - 1);
    int x2 = min(max((int)floorf(bx2 * sx), x1 + 1), WFD);
    int y2 = min(max((int)floorf(by2 * sy), y1 + 1), HFD);
    int Lx = x2 - x1, Ly = y2 - y1;

    // ---- gather phase: branch-free fat loads, 49 cells exactly ----
    {
        const float* Ibl = Ip + (size_t)b * HFD * WFD * CC + 4 * lane;
        const float* Obl = O + (size_t)b * NHB * WFD * CC + 4 * lane;
        unsigned short* pbs = (unsigned short*)Pb;

#define GATHER_CELL(cellv)                                                       \
        {                                                                        \
            int cell = (cellv);                                                  \
            int i_ = cell / SS, j_ = cell % SS;                                  \
            int rs_ = y1 + (i_ * Ly) / SS;                                       \
            int re_ = y1 + ((i_ + 1) * Ly + SS - 1) / SS;                        \
            int cs_ = x1 + (j_ * Lx) / SS;                                       \
            int ce_ = x1 + ((j_ + 1) * Lx + SS - 1) / SS;                        \
            int r1 = re_ - 1;                                                    \
            int r0 = max(rs_ - 1, 0);                                            \
            int c1 = ce_ - 1;                                                    \
            int c0 = max(cs_ - 1, 0);                                            \
            int hb1 = r1 >> 3, hb0 = r0 >> 3;                                    \
            float rm = (rs_ > 0) ? 1.f : 0.f;                                    \
            float cm = (cs_ > 0) ? 1.f : 0.f;                                    \
            f32x4 br = *(const f32x4*)(Ibl + ((size_t)(r1 * WFD + c1)) * CC)     \
                     + *(const f32x4*)(Obl + ((size_t)(hb1 * WFD + c1)) * CC);   \
            f32x4 tr = *(const f32x4*)(Ibl + ((size_t)(r0 * WFD + c1)) * CC)     \
                     + *(const f32x4*)(Obl + ((size_t)(hb0 * WFD + c1)) * CC);   \
            f32x4 bl = *(const f32x4*)(Ibl + ((size_t)(r1 * WFD + c0)) * CC)     \
                     + *(const f32x4*)(Obl + ((size_t)(hb1 * WFD + c0)) * CC);   \
            f32x4 tl = *(const f32x4*)(Ibl + ((size_t)(r0 * WFD + c0)) * CC)     \
                     + *(const f32x4*)(Obl + ((size_t)(hb0 * WFD + c0)) * CC);   \
            f32x4 s = (br - tr * rm) - (bl - tl * rm) * cm;                      \
            float inv = 1.f / ((float)(re_ - rs_) * (float)(ce_ - cs_));         \
            ushort4 pk;                                                          \
            {                                                                    \
                __hip_bfloat16 h0 = __float2bfloat16(s.x * inv);                 \
                __hip_bfloat16 h1 = __float2bfloat16(s.y * inv);                 \
                __hip_bfloat16 h2 = __float2bfloat16(s.z * inv);                 \
                __hip_bfloat16 h3 = __float2bfloat16(s.w * inv);                 \
                pk.x = *(unsigned short*)&h0;                                    \
                pk.y = *(unsigned short*)&h1;                                    \
                pk.z = *(unsigned short*)&h2;                                    \
                pk.w = *(unsigned short*)&h3;                                    \
            }                                                                    \
            *(ushort4*)(pbs + cell * PB_STRIDE + 4 * lane) = pk;                 \
        }

        #pragma unroll
        for (int k = 0; k < 6; ++k) GATHER_CELL(wv * 6 + k);
        if (wv == 0) GATHER_CELL(48);
#undef GATHER_CELL
    }
    __syncthreads();

    // ---- GEMM phase: wave wv owns o in [wv*32, wv*32+32) ----
    const int ln   = lane & 15;
    const int quad = lane >> 4;
    const int ob0  = wv * 32;

    f32x4 z = {0.f, 0.f, 0.f, 0.f};
    f32x4 acc[2][4];
    #pragma unroll
    for (int mt = 0; mt < 2; ++mt)
        #pragma unroll
        for (int nt = 0; nt < 4; ++nt) acc[mt][nt] = z;

    {
        const short* A = (const short*)Wb;
        #pragma unroll
        for (int k0 = 0; k0 < CC; k0 += 32) {
            short8 a[2], bf[4];
            #pragma unroll
            for (int mt = 0; mt < 2; ++mt)
                a[mt] = *(const short8*)(A + (ob0 + mt * 16 + ln) * CC + k0 + quad * 8);
            #pragma unroll
            for (int nt = 0; nt < 4; ++nt)
                bf[nt] = *(const short8*)((const short*)Pb + (nt * 16 + ln) * PB_STRIDE + k0 + quad * 8);
            #pragma unroll
            for (int mt = 0; mt < 2; ++mt)
                #pragma unroll
                for (int nt = 0; nt < 4; ++nt)
                    acc[mt][nt] = __builtin_amdgcn_mfma_f32_16x16x32_bf16(a[mt], bf[nt], acc[mt][nt], 0, 0, 0);
        }
    }

    // ---- epilogue: LDS-staged, coalesced f32x4 NT stores ----
    size_t obase = (size_t)bn * CC * 49;
    #pragma unroll
    for (int half = 0; half < 2; ++half) {
        __syncthreads();   // half0: GEMM reads of Pb done; half1: copy0 done
        if ((wv >> 2) == half) {
            int ob0l = (wv & 3) * 32;      // o offset within this half
            #pragma unroll
            for (int mt = 0; mt < 2; ++mt) {
                f32x4 bv = *(const f32x4*)(bias + ob0 + mt * 16 + quad * 4);
                #pragma unroll
                for (int nt = 0; nt < 4; ++nt) {
                    int cell = nt * 16 + ln;
                    if (cell < 49) {
                        #pragma unroll
                        for (int reg = 0; reg < 4; ++reg) {
                            int ol = ob0l + mt * 16 + quad * 4 + reg;
                            stage[ol * 49 + cell] = acc[mt][nt][reg] + bv[reg];
                        }
                    }
                }
            }
        }
        __syncthreads();
        const f32x4* sv = (const f32x4*)stage;
        float* gbase = out + obase + (size_t)half * (128 * 49);
        for (int i = t; i < (128 * 49) / 4; i += 512) {
            __builtin_nontemporal_store(sv[i], (f32x4*)(gbase + 4 * i));
        }
    }

    if (t == 0) {
        __builtin_nontemporal_store((bx2 - bx1) * (by2 - by1), &out[REGION_OUT_ELEMS + bn]);
    }
}

// ---------------------------------------------------------------------------
extern "C" void kernel_launch(void* const* d_in, const int* in_sizes, int n_in,
                              void* d_out, int out_size, void* d_ws, size_t ws_size,
                              hipStream_t stream) {
    const float* fm     = (const float*)d_in[0];
    const float* bboxes = (const float*)d_in[1];
    const float* W      = (const float*)d_in[2];
    const float* bias   = (const float*)d_in[3];
    const int*   ih     = (const int*)d_in[4];
    const int*   iw     = (const int*)d_in[5];
    float* out = (float*)d_out;

    __hip_bfloat16* Wb = (__hip_bfloat16*)d_ws;                    // 256*256 bf16 = 128 KB
    float* Ip = (float*)((char*)d_ws + (size_t)CC * CC * 2 + 256); // partial integral, c-fastest
    Ip = (float*)(((uintptr_t)Ip + 1023) & ~(uintptr_t)1023);
    float* O = (float*)((char*)Ip + (size_t)BB * HFD * WFD * CC * 4);  // block offsets, 26 MB
    O = (float*)(((uintptr_t)O + 1023) & ~(uintptr_t)1023);

    k0_convert_w<<<CC, 256, 0, stream>>>(W, Wb);
    k1_rowscan_block<<<BB * 8 * NHB, 128, 0, stream>>>(fm, Ip);
    k2_offsets<<<BB * WFD, 256, 0, stream>>>(Ip, O);
    k3_gather_gemm<<<BB * NN, 512, 0, stream>>>(Ip, O, Wb, bias, bboxes, ih, iw, out);
}

// Round 10
// 380.779 us; speedup vs baseline: 1.1910x; 1.1910x over previous
//
#include <hip/hip_runtime.h>
#include <hip/hip_bf16.h>

// Problem constants
#define BB 8
#define NN 128
#define CC 256
#define HFD 160
#define WFD 160
#define SS 7
#define HB 8                 // h-block size for hierarchical integral
#define NHB (HFD / HB)       // 20 blocks
#define REGION_OUT_ELEMS (8*128*256*49)   // 12,845,056

typedef short short8 __attribute__((ext_vector_type(8)));
typedef float f32x4  __attribute__((ext_vector_type(4)));

// ---------------------------------------------------------------------------
// K0: convert proj_w [o][c] fp32 -> bf16, row-major (A-operand friendly).
// ---------------------------------------------------------------------------
__global__ __launch_bounds__(256) void k0_convert_w(const float* __restrict__ W,
                                                    __hip_bfloat16* __restrict__ Wb) {
    int o = blockIdx.x;
    int c = threadIdx.x;
    Wb[o * CC + c] = __float2bfloat16(W[o * CC + c]);
}

// ---------------------------------------------------------------------------
// K1: fused transpose + w-cumsum + within-8-row-block h-cumsum.
//   in : fm[b][c][h][w]   (w fastest)
//   out: Ip[b][h][w][c]   (c fastest); Ip = w-prefix + h-prefix within block
// COALESCED staged load (R9's per-lane segment load was 64-lines-per-instr
// uncoalesced -> 2.5 TB/s; counters r9). Register prefetch double-buffer:
// next row's 10 f32x4 live in regs, issued after the stage write so HBM
// latency hides under scan+fixup+transpose. Scan is register-based via 40
// pipelined conflict-free ds_read_b32 (stride 161).
// ---------------------------------------------------------------------------
__global__ __launch_bounds__(128) void k1_rowscan_block(const float* __restrict__ fm,
                                                        float* __restrict__ Ip) {
    int bid = blockIdx.x;            // b*160 + c8*20 + hb
    int hb  = bid % NHB;
    int c8  = (bid / NHB) & 7;
    int b   = bid / (NHB * 8);
    int c0  = c8 * 32;
    int t   = threadIdx.x;

    __shared__ float tile[32][161];
    __shared__ float segsum[32][4];

    const int row = t & 31;
    const int seg = t >> 5;
    const int w0  = seg * 40;

    // coalesced stage mapping: vid = it*128 + t -> (c_l = vid/40, wq = vid%40)
    int cl_[10], wq_[10];
    #pragma unroll
    for (int it = 0; it < 10; ++it) {
        int vid = it * 128 + t;
        cl_[it] = vid / 40;
        wq_[it] = vid - cl_[it] * 40;
    }

    f32x4 csum[10];
    #pragma unroll
    for (int it = 0; it < 10; ++it) csum[it] = (f32x4){0.f, 0.f, 0.f, 0.f};

    // prefetch row 0 (coalesced)
    f32x4 pre[10];
    #pragma unroll
    for (int it = 0; it < 10; ++it)
        pre[it] = __builtin_nontemporal_load(
            (const f32x4*)(fm + (((size_t)(b * CC + c0 + cl_[it])) * HFD + hb * HB) * WFD + wq_[it] * 4));

    for (int hh = 0; hh < HB; ++hh) {
        __syncthreads();   // prev row's transpose readers done

        // stage current row from regs (f32x4 LDS writes)
        #pragma unroll
        for (int it = 0; it < 10; ++it)
            *(f32x4*)&tile[cl_[it]][wq_[it] * 4] = pre[it];

        // issue prefetch for next row (latency hidden under scan+transpose)
        if (hh + 1 < HB) {
            #pragma unroll
            for (int it = 0; it < 10; ++it)
                pre[it] = __builtin_nontemporal_load(
                    (const f32x4*)(fm + (((size_t)(b * CC + c0 + cl_[it])) * HFD + hb * HB + hh + 1) * WFD + wq_[it] * 4));
        }

        __syncthreads();   // stage visible

        // register scan: 40 independent conflict-free ds_read_b32
        float v[40];
        #pragma unroll
        for (int k = 0; k < 40; ++k) v[k] = tile[row][w0 + k];
        #pragma unroll
        for (int k = 1; k < 40; ++k) v[k] += v[k - 1];
        segsum[row][seg] = v[39];
        __syncthreads();   // segsum visible

        // writer-side segment offset + scanned write back (own range only)
        float off = 0.f;
        if (seg > 0) off += segsum[row][0];
        if (seg > 1) off += segsum[row][1];
        if (seg > 2) off += segsum[row][2];
        #pragma unroll
        for (int k = 0; k < 40; ++k) tile[row][w0 + k] = v[k] + off;
        __syncthreads();   // scanned tile visible

        // transposed read + running column sum + store
        int h = hb * HB + hh;
        size_t obase = (((size_t)b * HFD + h) * WFD) * CC + c0;
        #pragma unroll
        for (int it = 0; it < 10; ++it) {
            int vid = it * 128 + t;
            int w   = vid >> 3;        // 0..159
            int cg  = vid & 7;         // c = 4*cg within the 32-ch tile
            f32x4 cur;
            cur.x = tile[cg * 4 + 0][w];
            cur.y = tile[cg * 4 + 1][w];
            cur.z = tile[cg * 4 + 2][w];
            cur.w = tile[cg * 4 + 3][w];
            csum[it] += cur;
            *(f32x4*)(Ip + obase + (size_t)w * CC + cg * 4) = csum[it];
        }
    }
}

// ---------------------------------------------------------------------------
// K2': block-offset exclusive scan.  O[b][hb][w][c] = sum of block totals of
// all h-blocks before hb; block total of k = Ip[b][8k+7][w][c].
// One WG per (b,w), thread = c.  26 MB read + 26 MB write (tiny).
// ---------------------------------------------------------------------------
__global__ __launch_bounds__(256) void k2_offsets(const float* __restrict__ Ip,
                                                  float* __restrict__ O) {
    int w = blockIdx.x % WFD;
    int b = blockIdx.x / WFD;
    int c = threadIdx.x;
    float run = 0.f;
    #pragma unroll
    for (int hb = 0; hb < NHB; ++hb) {
        O[(((size_t)b * NHB + hb) * WFD + w) * CC + c] = run;
        run += Ip[(((size_t)b * HFD + (hb * HB + HB - 1)) * WFD + w) * CC + c];
    }
}

// ---------------------------------------------------------------------------
// K3: fused gather + GEMM, 512 threads (8 waves).
// bn swizzled so image b == XCD id.  Corner value = Ip(r,·) + O(r>>3,·).
// Gather: wave wv owns cells wv*6+k (k=0..5); wave 0 additionally cell 48.
// GEMM: wave wv owns o in [wv*32, wv*32+32): acc[2][4], 64 MFMA/wave.
// Epilogue: LDS-staged coalesced f32x4 NT stores.
// ---------------------------------------------------------------------------
#define PB_STRIDE 264   // bf16 elems; 528 B row

__global__ __launch_bounds__(512, 4) void k3_gather_gemm(
        const float* __restrict__ Ip, const float* __restrict__ O,
        const __hip_bfloat16* __restrict__ Wb,
        const float* __restrict__ bias, const float* __restrict__ bboxes,
        const int* __restrict__ ih_p, const int* __restrict__ iw_p,
        float* __restrict__ out) {
    int bid = blockIdx.x;
    int bn  = ((bid & 7) << 7) | (bid >> 3);   // image = bid&7 -> one image per XCD
    int b   = bn >> 7;
    int t   = threadIdx.x;
    const int lane = t & 63;
    const int wv   = t >> 6;     // 0..7

    __shared__ __align__(16) __hip_bfloat16 Pb[64 * PB_STRIDE];   // 33 KB
    float* stage = (float*)Pb;   // reused after GEMM: 128 o x 49 cells = 25 KB

    float bx1 = bboxes[bn * 4 + 0];
    float by1 = bboxes[bn * 4 + 1];
    float bx2 = bboxes[bn * 4 + 2];
    float by2 = bboxes[bn * 4 + 3];
    float sx = (float)WFD / (float)iw_p[0];
    float sy = (float)HFD / (float)ih_p[0];

    int x1 = min(max((int)floorf(bx1 * sx), 0), WFD - 1);
    int y1 = min(max((int)floorf(by1 * sy), 0), HFD - 1);
    int x2 = min(max((int)floorf(bx2 * sx), x1 + 1), WFD);
    int y2 = min(max((int)floorf(by2 * sy), y1 + 1), HFD);
    int Lx = x2 - x1, Ly = y2 - y1;

    // ---- gather phase: branch-free fat loads, 49 cells exactly ----
    {
        const float* Ibl = Ip + (size_t)b * HFD * WFD * CC + 4 * lane;
        const float* Obl = O + (size_t)b * NHB * WFD * CC + 4 * lane;
        unsigned short* pbs = (unsigned short*)Pb;

#define GATHER_CELL(cellv)                                                       \
        {                                                                        \
            int cell = (cellv);                                                  \
            int i_ = cell / SS, j_ = cell % SS;                                  \
            int rs_ = y1 + (i_ * Ly) / SS;                                       \
            int re_ = y1 + ((i_ + 1) * Ly + SS - 1) / SS;                        \
            int cs_ = x1 + (j_ * Lx) / SS;                                       \
            int ce_ = x1 + ((j_ + 1) * Lx + SS - 1) / SS;                        \
            int r1 = re_ - 1;                                                    \
            int r0 = max(rs_ - 1, 0);                                            \
            int c1 = ce_ - 1;                                                    \
            int c0 = max(cs_ - 1, 0);                                            \
            int hb1 = r1 >> 3, hb0 = r0 >> 3;                                    \
            float rm = (rs_ > 0) ? 1.f : 0.f;                                    \
            float cm = (cs_ > 0) ? 1.f : 0.f;                                    \
            f32x4 br = *(const f32x4*)(Ibl + ((size_t)(r1 * WFD + c1)) * CC)     \
                     + *(const f32x4*)(Obl + ((size_t)(hb1 * WFD + c1)) * CC);   \
            f32x4 tr = *(const f32x4*)(Ibl + ((size_t)(r0 * WFD + c1)) * CC)     \
                     + *(const f32x4*)(Obl + ((size_t)(hb0 * WFD + c1)) * CC);   \
            f32x4 bl = *(const f32x4*)(Ibl + ((size_t)(r1 * WFD + c0)) * CC)     \
                     + *(const f32x4*)(Obl + ((size_t)(hb1 * WFD + c0)) * CC);   \
            f32x4 tl = *(const f32x4*)(Ibl + ((size_t)(r0 * WFD + c0)) * CC)     \
                     + *(const f32x4*)(Obl + ((size_t)(hb0 * WFD + c0)) * CC);   \
            f32x4 s = (br - tr * rm) - (bl - tl * rm) * cm;                      \
            float inv = 1.f / ((float)(re_ - rs_) * (float)(ce_ - cs_));         \
            ushort4 pk;                                                          \
            {                                                                    \
                __hip_bfloat16 h0 = __float2bfloat16(s.x * inv);                 \
                __hip_bfloat16 h1 = __float2bfloat16(s.y * inv);                 \
                __hip_bfloat16 h2 = __float2bfloat16(s.z * inv);                 \
                __hip_bfloat16 h3 = __float2bfloat16(s.w * inv);                 \
                pk.x = *(unsigned short*)&h0;                                    \
                pk.y = *(unsigned short*)&h1;                                    \
                pk.z = *(unsigned short*)&h2;                                    \
                pk.w = *(unsigned short*)&h3;                                    \
            }                                                                    \
            *(ushort4*)(pbs + cell * PB_STRIDE + 4 * lane) = pk;                 \
        }

        #pragma unroll
        for (int k = 0; k < 6; ++k) GATHER_CELL(wv * 6 + k);
        if (wv == 0) GATHER_CELL(48);
#undef GATHER_CELL
    }
    __syncthreads();

    // ---- GEMM phase: wave wv owns o in [wv*32, wv*32+32) ----
    const int ln   = lane & 15;
    const int quad = lane >> 4;
    const int ob0  = wv * 32;

    f32x4 z = {0.f, 0.f, 0.f, 0.f};
    f32x4 acc[2][4];
    #pragma unroll
    for (int mt = 0; mt < 2; ++mt)
        #pragma unroll
        for (int nt = 0; nt < 4; ++nt) acc[mt][nt] = z;

    {
        const short* A = (const short*)Wb;
        #pragma unroll
        for (int k0 = 0; k0 < CC; k0 += 32) {
            short8 a[2], bf[4];
            #pragma unroll
            for (int mt = 0; mt < 2; ++mt)
                a[mt] = *(const short8*)(A + (ob0 + mt * 16 + ln) * CC + k0 + quad * 8);
            #pragma unroll
            for (int nt = 0; nt < 4; ++nt)
                bf[nt] = *(const short8*)((const short*)Pb + (nt * 16 + ln) * PB_STRIDE + k0 + quad * 8);
            #pragma unroll
            for (int mt = 0; mt < 2; ++mt)
                #pragma unroll
                for (int nt = 0; nt < 4; ++nt)
                    acc[mt][nt] = __builtin_amdgcn_mfma_f32_16x16x32_bf16(a[mt], bf[nt], acc[mt][nt], 0, 0, 0);
        }
    }

    // ---- epilogue: LDS-staged, coalesced f32x4 NT stores ----
    size_t obase = (size_t)bn * CC * 49;
    #pragma unroll
    for (int half = 0; half < 2; ++half) {
        __syncthreads();   // half0: GEMM reads of Pb done; half1: copy0 done
        if ((wv >> 2) == half) {
            int ob0l = (wv & 3) * 32;      // o offset within this half
            #pragma unroll
            for (int mt = 0; mt < 2; ++mt) {
                f32x4 bv = *(const f32x4*)(bias + ob0 + mt * 16 + quad * 4);
                #pragma unroll
                for (int nt = 0; nt < 4; ++nt) {
                    int cell = nt * 16 + ln;
                    if (cell < 49) {
                        #pragma unroll
                        for (int reg = 0; reg < 4; ++reg) {
                            int ol = ob0l + mt * 16 + quad * 4 + reg;
                            stage[ol * 49 + cell] = acc[mt][nt][reg] + bv[reg];
                        }
                    }
                }
            }
        }
        __syncthreads();
        const f32x4* sv = (const f32x4*)stage;
        float* gbase = out + obase + (size_t)half * (128 * 49);
        for (int i = t; i < (128 * 49) / 4; i += 512) {
            __builtin_nontemporal_store(sv[i], (f32x4*)(gbase + 4 * i));
        }
    }

    if (t == 0) {
        __builtin_nontemporal_store((bx2 - bx1) * (by2 - by1), &out[REGION_OUT_ELEMS + bn]);
    }
}

// ---------------------------------------------------------------------------
extern "C" void kernel_launch(void* const* d_in, const int* in_sizes, int n_in,
                              void* d_out, int out_size, void* d_ws, size_t ws_size,
                              hipStream_t stream) {
    const float* fm     = (const float*)d_in[0];
    const float* bboxes = (const float*)d_in[1];
    const float* W      = (const float*)d_in[2];
    const float* bias   = (const float*)d_in[3];
    const int*   ih     = (const int*)d_in[4];
    const int*   iw     = (const int*)d_in[5];
    float* out = (float*)d_out;

    __hip_bfloat16* Wb = (__hip_bfloat16*)d_ws;                    // 256*256 bf16 = 128 KB
    float* Ip = (float*)((char*)d_ws + (size_t)CC * CC * 2 + 256); // partial integral, c-fastest
    Ip = (float*)(((uintptr_t)Ip + 1023) & ~(uintptr_t)1023);
    float* O = (float*)((char*)Ip + (size_t)BB * HFD * WFD * CC * 4);  // block offsets, 26 MB
    O = (float*)(((uintptr_t)O + 1023) & ~(uintptr_t)1023);

    k0_convert_w<<<CC, 256, 0, stream>>>(W, Wb);
    k1_rowscan_block<<<BB * 8 * NHB, 128, 0, stream>>>(fm, Ip);
    k2_offsets<<<BB * WFD, 256, 0, stream>>>(Ip, O);
    k3_gather_gemm<<<BB * NN, 512, 0, stream>>>(Ip, O, Wb, bias, bboxes, ih, iw, out);
}

// Round 11
// 379.376 us; speedup vs baseline: 1.1954x; 1.0037x over previous
//
#include <hip/hip_runtime.h>
#include <hip/hip_bf16.h>

// Problem constants
#define BB 8
#define NN 128
#define CC 256
#define HFD 160
#define WFD 160
#define SS 7
#define HB 8                 // h-block size for hierarchical integral
#define NHB (HFD / HB)       // 20 blocks
#define REGION_OUT_ELEMS (8*128*256*49)   // 12,845,056

typedef short short8 __attribute__((ext_vector_type(8)));
typedef float f32x4  __attribute__((ext_vector_type(4)));

// ---------------------------------------------------------------------------
// K0: convert proj_w [o][c] fp32 -> bf16, row-major (A-operand friendly).
// ---------------------------------------------------------------------------
__global__ __launch_bounds__(256) void k0_convert_w(const float* __restrict__ W,
                                                    __hip_bfloat16* __restrict__ Wb) {
    int o = blockIdx.x;
    int c = threadIdx.x;
    Wb[o * CC + c] = __float2bfloat16(W[o * CC + c]);
}

// ---------------------------------------------------------------------------
// K1: fused transpose + w-cumsum + within-8-row-block h-cumsum.
//   in : fm[b][c][h][w]   (w fastest)
//   out: Ip[b][h][w][c]   (c fastest); Ip = w-prefix + h-prefix within block
// Thread remap (row = t>>2, seg = t&3): a row's 4 segments sit in ADJACENT
// LANES of one wave -> segment offsets exchanged with 3 __shfl (no segsum
// LDS, no barrier). Scan write-back hits only the thread's own cells (no
// barrier vs scan-read). 3 barriers/row (was 4), one LDS phase removed.
// Coalesced stage + register prefetch double-buffer kept from R10.
// Scan-phase bank pattern: row + 8*seg + k mod 32 -> 2-way = free (m136).
// ---------------------------------------------------------------------------
__global__ __launch_bounds__(128) void k1_rowscan_block(const float* __restrict__ fm,
                                                        float* __restrict__ Ip) {
    int bid = blockIdx.x;            // b*160 + c8*20 + hb
    int hb  = bid % NHB;
    int c8  = (bid / NHB) & 7;
    int b   = bid / (NHB * 8);
    int c0  = c8 * 32;
    int t   = threadIdx.x;

    __shared__ float tile[32][161];

    const int row = t >> 2;          // 0..31
    const int seg = t & 3;           // 0..3
    const int w0  = seg * 40;
    const int lg  = (t & 63) & ~3;   // lane-group base within wave

    // coalesced stage mapping: vid = it*128 + t -> (c_l = vid/40, wq = vid%40)
    int cl_[10], wq_[10];
    #pragma unroll
    for (int it = 0; it < 10; ++it) {
        int vid = it * 128 + t;
        cl_[it] = vid / 40;
        wq_[it] = vid - cl_[it] * 40;
    }

    f32x4 csum[10];
    #pragma unroll
    for (int it = 0; it < 10; ++it) csum[it] = (f32x4){0.f, 0.f, 0.f, 0.f};

    // prefetch row 0 (coalesced)
    f32x4 pre[10];
    #pragma unroll
    for (int it = 0; it < 10; ++it)
        pre[it] = __builtin_nontemporal_load(
            (const f32x4*)(fm + (((size_t)(b * CC + c0 + cl_[it])) * HFD + hb * HB) * WFD + wq_[it] * 4));

    for (int hh = 0; hh < HB; ++hh) {
        __syncthreads();   // B1: prev row's transpose readers done

        // stage current row from regs (f32x4 LDS writes)
        #pragma unroll
        for (int it = 0; it < 10; ++it)
            *(f32x4*)&tile[cl_[it]][wq_[it] * 4] = pre[it];

        // issue prefetch for next row (latency hidden under scan+transpose)
        if (hh + 1 < HB) {
            #pragma unroll
            for (int it = 0; it < 10; ++it)
                pre[it] = __builtin_nontemporal_load(
                    (const f32x4*)(fm + (((size_t)(b * CC + c0 + cl_[it])) * HFD + hb * HB + hh + 1) * WFD + wq_[it] * 4));
        }

        __syncthreads();   // B2: stage visible

        // register scan of own 40-element segment (2-way-free LDS reads)
        float v[40];
        #pragma unroll
        for (int k = 0; k < 40; ++k) v[k] = tile[row][w0 + k];
        #pragma unroll
        for (int k = 1; k < 40; ++k) v[k] += v[k - 1];

        // segment offsets via in-wave shuffles (adjacent lanes = same row)
        float total = v[39];
        float t0 = __shfl(total, lg + 0);
        float t1 = __shfl(total, lg + 1);
        float t2 = __shfl(total, lg + 2);
        float off = 0.f;
        if (seg > 0) off += t0;
        if (seg > 1) off += t1;
        if (seg > 2) off += t2;

        // write back to own cells only (no hazard before B3)
        #pragma unroll
        for (int k = 0; k < 40; ++k) tile[row][w0 + k] = v[k] + off;

        __syncthreads();   // B3: scanned tile visible

        // transposed read + running column sum + store
        int h = hb * HB + hh;
        size_t obase = (((size_t)b * HFD + h) * WFD) * CC + c0;
        #pragma unroll
        for (int it = 0; it < 10; ++it) {
            int vid = it * 128 + t;
            int w   = vid >> 3;        // 0..159
            int cg  = vid & 7;         // c = 4*cg within the 32-ch tile
            f32x4 cur;
            cur.x = tile[cg * 4 + 0][w];
            cur.y = tile[cg * 4 + 1][w];
            cur.z = tile[cg * 4 + 2][w];
            cur.w = tile[cg * 4 + 3][w];
            csum[it] += cur;
            *(f32x4*)(Ip + obase + (size_t)w * CC + cg * 4) = csum[it];
        }
    }
}

// ---------------------------------------------------------------------------
// K2': block-offset exclusive scan.  O[b][hb][w][c] = sum of block totals of
// all h-blocks before hb; block total of k = Ip[b][8k+7][w][c].
// One WG per (b,w), thread = c.  26 MB read + 26 MB write (tiny).
// ---------------------------------------------------------------------------
__global__ __launch_bounds__(256) void k2_offsets(const float* __restrict__ Ip,
                                                  float* __restrict__ O) {
    int w = blockIdx.x % WFD;
    int b = blockIdx.x / WFD;
    int c = threadIdx.x;
    float run = 0.f;
    #pragma unroll
    for (int hb = 0; hb < NHB; ++hb) {
        O[(((size_t)b * NHB + hb) * WFD + w) * CC + c] = run;
        run += Ip[(((size_t)b * HFD + (hb * HB + HB - 1)) * WFD + w) * CC + c];
    }
}

// ---------------------------------------------------------------------------
// K3: fused gather + GEMM, 512 threads (8 waves).
// bn swizzled so image b == XCD id.  Corner value = Ip(r,·) + O(r>>3,·).
// Gather: wave wv owns cells wv*6+k (k=0..5); wave 0 additionally cell 48.
// GEMM: wave wv owns o in [wv*32, wv*32+32): acc[2][4], 64 MFMA/wave.
// Epilogue: LDS-staged coalesced f32x4 NT stores.
// ---------------------------------------------------------------------------
#define PB_STRIDE 264   // bf16 elems; 528 B row

__global__ __launch_bounds__(512, 4) void k3_gather_gemm(
        const float* __restrict__ Ip, const float* __restrict__ O,
        const __hip_bfloat16* __restrict__ Wb,
        const float* __restrict__ bias, const float* __restrict__ bboxes,
        const int* __restrict__ ih_p, const int* __restrict__ iw_p,
        float* __restrict__ out) {
    int bid = blockIdx.x;
    int bn  = ((bid & 7) << 7) | (bid >> 3);   // image = bid&7 -> one image per XCD
    int b   = bn >> 7;
    int t   = threadIdx.x;
    const int lane = t & 63;
    const int wv   = t >> 6;     // 0..7

    __shared__ __align__(16) __hip_bfloat16 Pb[64 * PB_STRIDE];   // 33 KB
    float* stage = (float*)Pb;   // reused after GEMM: 128 o x 49 cells = 25 KB

    float bx1 = bboxes[bn * 4 + 0];
    float by1 = bboxes[bn * 4 + 1];
    float bx2 = bboxes[bn * 4 + 2];
    float by2 = bboxes[bn * 4 + 3];
    float sx = (float)WFD / (float)iw_p[0];
    float sy = (float)HFD / (float)ih_p[0];

    int x1 = min(max((int)floorf(bx1 * sx), 0), WFD - 1);
    int y1 = min(max((int)floorf(by1 * sy), 0), HFD - 1);
    int x2 = min(max((int)floorf(bx2 * sx), x1 + 1), WFD);
    int y2 = min(max((int)floorf(by2 * sy), y1 + 1), HFD);
    int Lx = x2 - x1, Ly = y2 - y1;

    // ---- gather phase: branch-free fat loads, 49 cells exactly ----
    {
        const float* Ibl = Ip + (size_t)b * HFD * WFD * CC + 4 * lane;
        const float* Obl = O + (size_t)b * NHB * WFD * CC + 4 * lane;
        unsigned short* pbs = (unsigned short*)Pb;

#define GATHER_CELL(cellv)                                                       \
        {                                                                        \
            int cell = (cellv);                                                  \
            int i_ = cell / SS, j_ = cell % SS;                                  \
            int rs_ = y1 + (i_ * Ly) / SS;                                       \
            int re_ = y1 + ((i_ + 1) * Ly + SS - 1) / SS;                        \
            int cs_ = x1 + (j_ * Lx) / SS;                                       \
            int ce_ = x1 + ((j_ + 1) * Lx + SS - 1) / SS;                        \
            int r1 = re_ - 1;                                                    \
            int r0 = max(rs_ - 1, 0);                                            \
            int c1 = ce_ - 1;                                                    \
            int c0 = max(cs_ - 1, 0);                                            \
            int hb1 = r1 >> 3, hb0 = r0 >> 3;                                    \
            float rm = (rs_ > 0) ? 1.f : 0.f;                                    \
            float cm = (cs_ > 0) ? 1.f : 0.f;                                    \
            f32x4 br = *(const f32x4*)(Ibl + ((size_t)(r1 * WFD + c1)) * CC)     \
                     + *(const f32x4*)(Obl + ((size_t)(hb1 * WFD + c1)) * CC);   \
            f32x4 tr = *(const f32x4*)(Ibl + ((size_t)(r0 * WFD + c1)) * CC)     \
                     + *(const f32x4*)(Obl + ((size_t)(hb0 * WFD + c1)) * CC);   \
            f32x4 bl = *(const f32x4*)(Ibl + ((size_t)(r1 * WFD + c0)) * CC)     \
                     + *(const f32x4*)(Obl + ((size_t)(hb1 * WFD + c0)) * CC);   \
            f32x4 tl = *(const f32x4*)(Ibl + ((size_t)(r0 * WFD + c0)) * CC)     \
                     + *(const f32x4*)(Obl + ((size_t)(hb0 * WFD + c0)) * CC);   \
            f32x4 s = (br - tr * rm) - (bl - tl * rm) * cm;                      \
            float inv = 1.f / ((float)(re_ - rs_) * (float)(ce_ - cs_));         \
            ushort4 pk;                                                          \
            {                                                                    \
                __hip_bfloat16 h0 = __float2bfloat16(s.x * inv);                 \
                __hip_bfloat16 h1 = __float2bfloat16(s.y * inv);                 \
                __hip_bfloat16 h2 = __float2bfloat16(s.z * inv);                 \
                __hip_bfloat16 h3 = __float2bfloat16(s.w * inv);                 \
                pk.x = *(unsigned short*)&h0;                                    \
                pk.y = *(unsigned short*)&h1;                                    \
                pk.z = *(unsigned short*)&h2;                                    \
                pk.w = *(unsigned short*)&h3;                                    \
            }                                                                    \
            *(ushort4*)(pbs + cell * PB_STRIDE + 4 * lane) = pk;                 \
        }

        #pragma unroll
        for (int k = 0; k < 6; ++k) GATHER_CELL(wv * 6 + k);
        if (wv == 0) GATHER_CELL(48);
#undef GATHER_CELL
    }
    __syncthreads();

    // ---- GEMM phase: wave wv owns o in [wv*32, wv*32+32) ----
    const int ln   = lane & 15;
    const int quad = lane >> 4;
    const int ob0  = wv * 32;

    f32x4 z = {0.f, 0.f, 0.f, 0.f};
    f32x4 acc[2][4];
    #pragma unroll
    for (int mt = 0; mt < 2; ++mt)
        #pragma unroll
        for (int nt = 0; nt < 4; ++nt) acc[mt][nt] = z;

    {
        const short* A = (const short*)Wb;
        #pragma unroll
        for (int k0 = 0; k0 < CC; k0 += 32) {
            short8 a[2], bf[4];
            #pragma unroll
            for (int mt = 0; mt < 2; ++mt)
                a[mt] = *(const short8*)(A + (ob0 + mt * 16 + ln) * CC + k0 + quad * 8);
            #pragma unroll
            for (int nt = 0; nt < 4; ++nt)
                bf[nt] = *(const short8*)((const short*)Pb + (nt * 16 + ln) * PB_STRIDE + k0 + quad * 8);
            #pragma unroll
            for (int mt = 0; mt < 2; ++mt)
                #pragma unroll
                for (int nt = 0; nt < 4; ++nt)
                    acc[mt][nt] = __builtin_amdgcn_mfma_f32_16x16x32_bf16(a[mt], bf[nt], acc[mt][nt], 0, 0, 0);
        }
    }

    // ---- epilogue: LDS-staged, coalesced f32x4 NT stores ----
    size_t obase = (size_t)bn * CC * 49;
    #pragma unroll
    for (int half = 0; half < 2; ++half) {
        __syncthreads();   // half0: GEMM reads of Pb done; half1: copy0 done
        if ((wv >> 2) == half) {
            int ob0l = (wv & 3) * 32;      // o offset within this half
            #pragma unroll
            for (int mt = 0; mt < 2; ++mt) {
                f32x4 bv = *(const f32x4*)(bias + ob0 + mt * 16 + quad * 4);
                #pragma unroll
                for (int nt = 0; nt < 4; ++nt) {
                    int cell = nt * 16 + ln;
                    if (cell < 49) {
                        #pragma unroll
                        for (int reg = 0; reg < 4; ++reg) {
                            int ol = ob0l + mt * 16 + quad * 4 + reg;
                            stage[ol * 49 + cell] = acc[mt][nt][reg] + bv[reg];
                        }
                    }
                }
            }
        }
        __syncthreads();
        const f32x4* sv = (const f32x4*)stage;
        float* gbase = out + obase + (size_t)half * (128 * 49);
        for (int i = t; i < (128 * 49) / 4; i += 512) {
            __builtin_nontemporal_store(sv[i], (f32x4*)(gbase + 4 * i));
        }
    }

    if (t == 0) {
        __builtin_nontemporal_store((bx2 - bx1) * (by2 - by1), &out[REGION_OUT_ELEMS + bn]);
    }
}

// ---------------------------------------------------------------------------
extern "C" void kernel_launch(void* const* d_in, const int* in_sizes, int n_in,
                              void* d_out, int out_size, void* d_ws, size_t ws_size,
                              hipStream_t stream) {
    const float* fm     = (const float*)d_in[0];
    const float* bboxes = (const float*)d_in[1];
    const float* W      = (const float*)d_in[2];
    const float* bias   = (const float*)d_in[3];
    const int*   ih     = (const int*)d_in[4];
    const int*   iw     = (const int*)d_in[5];
    float* out = (float*)d_out;

    __hip_bfloat16* Wb = (__hip_bfloat16*)d_ws;                    // 256*256 bf16 = 128 KB
    float* Ip = (float*)((char*)d_ws + (size_t)CC * CC * 2 + 256); // partial integral, c-fastest
    Ip = (float*)(((uintptr_t)Ip + 1023) & ~(uintptr_t)1023);
    float* O = (float*)((char*)Ip + (size_t)BB * HFD * WFD * CC * 4);  // block offsets, 26 MB
    O = (float*)(((uintptr_t)O + 1023) & ~(uintptr_t)1023);

    k0_convert_w<<<CC, 256, 0, stream>>>(W, Wb);
    k1_rowscan_block<<<BB * 8 * NHB, 128, 0, stream>>>(fm, Ip);
    k2_offsets<<<BB * WFD, 256, 0, stream>>>(Ip, O);
    k3_gather_gemm<<<BB * NN, 512, 0, stream>>>(Ip, O, Wb, bias, bboxes, ih, iw, out);
}